// Round 2
// baseline (577.882 us; speedup 1.0000x reference)
//
#include <hip/hip_runtime.h>
#include <hip/hip_bf16.h>

#define B_TOK 2048
#define D_DIM 1024
#define E_NUM 8
#define H_DIM 4096
#define C_DIM 1024
#define CAP   5120
#define MAXT  40

typedef __attribute__((ext_vector_type(8))) short bf16x8;
typedef __attribute__((ext_vector_type(4))) float floatx4;

__device__ __forceinline__ unsigned short f2bf(float f) {
  union { float f; unsigned int u; } a; a.f = f;
  unsigned int u = a.u;
  return (unsigned short)((u + 0x7FFFu + ((u >> 16) & 1u)) >> 16);
}

__device__ __forceinline__ void gload_lds16(const void* g, void* l) {
  __builtin_amdgcn_global_load_lds(
      (const __attribute__((address_space(1))) void*)g,
      (__attribute__((address_space(3))) void*)l, 16, 0, 0);
}

// ---------------- init: zero out_acc, counts, slot_tok = -1 ----------------
__global__ __launch_bounds__(256) void kinit(float* out_acc, int* slot_tok, int* counts) {
  int id = blockIdx.x * 256 + threadIdx.x;   // grid sized exactly B_TOK*C_DIM
  out_acc[id] = 0.f;
  if (id < CAP) slot_tok[id] = -1;
  if (id < E_NUM) counts[id] = 0;
}

// ---------------- router: logits, top2, softmax, LN stats ----------------
__global__ __launch_bounds__(256) void krouter(const float* __restrict__ x,
                                               const float* __restrict__ Wr,
                                               const float* __restrict__ br,
                                               int2* meta_i, float4* meta_f, int* counts) {
  int b = blockIdx.x, t = threadIdx.x;
  const float4 xv = *(const float4*)(x + (size_t)b * D_DIM + t * 4);
  float v[10];
  v[0] = xv.x + xv.y + xv.z + xv.w;
  v[1] = xv.x * xv.x + xv.y * xv.y + xv.z * xv.z + xv.w * xv.w;
#pragma unroll
  for (int e = 0; e < 8; e++) v[2 + e] = 0.f;
  const float* wr = Wr + (size_t)(t * 4) * E_NUM;
  float xs[4] = {xv.x, xv.y, xv.z, xv.w};
#pragma unroll
  for (int j = 0; j < 4; j++) {
    float4 wa = *(const float4*)(wr + j * 8);
    float4 wb = *(const float4*)(wr + j * 8 + 4);
    v[2] += xs[j] * wa.x; v[3] += xs[j] * wa.y; v[4] += xs[j] * wa.z; v[5] += xs[j] * wa.w;
    v[6] += xs[j] * wb.x; v[7] += xs[j] * wb.y; v[8] += xs[j] * wb.z; v[9] += xs[j] * wb.w;
  }
#pragma unroll
  for (int i = 0; i < 10; i++) {
    float s = v[i];
#pragma unroll
    for (int off = 32; off > 0; off >>= 1) s += __shfl_down(s, off, 64);
    v[i] = s;
  }
  __shared__ float red[4][10];
  int lane = t & 63, wid = t >> 6;
  if (lane == 0) {
#pragma unroll
    for (int i = 0; i < 10; i++) red[wid][i] = v[i];
  }
  __syncthreads();
  if (t == 0) {
    float f[10];
#pragma unroll
    for (int i = 0; i < 10; i++) f[i] = red[0][i] + red[1][i] + red[2][i] + red[3][i];
    float mu = f[0] * (1.f / 1024.f);
    float var = f[1] * (1.f / 1024.f) - mu * mu;
    float rsig = rsqrtf(var + 1e-5f);
    float lg[8];
#pragma unroll
    for (int e = 0; e < 8; e++) lg[e] = f[2 + e] + br[e];
    int i0 = 0;
#pragma unroll
    for (int e = 1; e < 8; e++) if (lg[e] > lg[i0]) i0 = e;
    int i1 = (i0 == 0) ? 1 : 0;
#pragma unroll
    for (int e = 0; e < 8; e++) if (e != i0 && lg[e] > lg[i1]) i1 = e;
    float ex = expf(lg[i1] - lg[i0]);       // <= 1
    float w0 = 1.f / (1.f + ex);
    float w1 = 1.f - w0;
    atomicAdd(counts + i0, 1);
    atomicAdd(counts + i1, 1);
    meta_i[b] = make_int2(i0, i1);
    meta_f[b] = make_float4(w0, w1, mu, rsig);
  }
}

// ---------------- prefix: 128-aligned segments + tile map ----------------
__global__ void kprefix(const int* counts, int* cursor, int* tmap_e, int* tmap_r) {
  if (threadIdx.x == 0) {
    int total = 0, tt = 0;
    for (int e = 0; e < E_NUM; e++) {
      cursor[e] = total;
      int nt = (counts[e] + 127) >> 7;
      for (int i = 0; i < nt; i++) { tmap_e[tt] = e; tmap_r[tt] = total + i * 128; tt++; }
      total += nt << 7;
    }
    for (; tt < MAXT; tt++) tmap_e[tt] = -1;
  }
}

// ---------------- scatter: slot assign + xe (bf16) ----------------
__global__ __launch_bounds__(256) void kscatter(const float* __restrict__ x,
                                                const float* __restrict__ ln_g,
                                                const float* __restrict__ ln_b,
                                                const int2* __restrict__ meta_i,
                                                const float4* __restrict__ meta_f,
                                                int* cursor, int* slot_tok, float* slot_w,
                                                unsigned short* __restrict__ xe) {
  int b = blockIdx.x, t = threadIdx.x;
  __shared__ int se[2], ss[2];
  __shared__ float smu, srs;
  if (t == 0) {
    int2 mi = meta_i[b];
    float4 mf = meta_f[b];
    int s0 = atomicAdd(cursor + mi.x, 1);
    int s1 = atomicAdd(cursor + mi.y, 1);
    slot_tok[s0] = b; slot_w[s0] = mf.x;
    slot_tok[s1] = b; slot_w[s1] = mf.y;
    se[0] = mi.x; se[1] = mi.y; ss[0] = s0; ss[1] = s1;
    smu = mf.z; srs = mf.w;
  }
  __syncthreads();
  int i = t * 4;
  float4 xv = *(const float4*)(x + (size_t)b * D_DIM + i);
  float mu = smu, rs = srs;
  float xn0 = (xv.x - mu) * rs, xn1 = (xv.y - mu) * rs, xn2 = (xv.z - mu) * rs, xn3 = (xv.w - mu) * rs;
#pragma unroll
  for (int k = 0; k < 2; k++) {
    int e = se[k], s = ss[k];
    float4 g = *(const float4*)(ln_g + (size_t)e * D_DIM + i);
    float4 bb = *(const float4*)(ln_b + (size_t)e * D_DIM + i);
    union { unsigned short us[4]; uint2 v; } u;
    u.us[0] = f2bf(xn0 * g.x + bb.x);
    u.us[1] = f2bf(xn1 * g.y + bb.y);
    u.us[2] = f2bf(xn2 * g.z + bb.z);
    u.us[3] = f2bf(xn3 * g.w + bb.w);
    *(uint2*)(xe + (size_t)s * D_DIM + i) = u.v;
  }
}

// ---------------- transpose+convert: src f32 [z][R][C] -> dst bf16 [z][C][R] ----------------
__global__ __launch_bounds__(256) void ktranspose(const float* __restrict__ src,
                                                  unsigned short* __restrict__ dst,
                                                  int R, int C) {
  __shared__ float tile[64][65];
  int z = blockIdx.z;
  const float* s = src + (size_t)z * R * C;
  unsigned short* d = dst + (size_t)z * R * C;
  int cx = blockIdx.x * 64, ry = blockIdx.y * 64;
  int t = threadIdx.x;
  int cl4 = (t & 15) * 4, rl = t >> 4;
#pragma unroll
  for (int p = 0; p < 4; p++) {
    int r = rl + p * 16;
    float4 v = *(const float4*)(s + (size_t)(ry + r) * C + cx + cl4);
    tile[r][cl4] = v.x; tile[r][cl4 + 1] = v.y; tile[r][cl4 + 2] = v.z; tile[r][cl4 + 3] = v.w;
  }
  __syncthreads();
#pragma unroll
  for (int p = 0; p < 4; p++) {
    int c = rl + p * 16;   // src col -> dst row
    union { unsigned short us[4]; uint2 v; } u;
    u.us[0] = f2bf(tile[cl4][c]);
    u.us[1] = f2bf(tile[cl4 + 1][c]);
    u.us[2] = f2bf(tile[cl4 + 2][c]);
    u.us[3] = f2bf(tile[cl4 + 3][c]);
    *(uint2*)(d + (size_t)(cx + c) * R + ry + cl4) = u.v;
  }
}

// ---------------- GEMM1: h = gelu(xe @ W1[e] + b1[e]), bf16 out ----------------
__global__ __launch_bounds__(256) void kgemm1(const unsigned short* __restrict__ xe,
                                              const unsigned short* __restrict__ w1t,
                                              const float* __restrict__ b1,
                                              unsigned short* __restrict__ h,
                                              const int* __restrict__ tmap_e,
                                              const int* __restrict__ tmap_r) {
  int e = tmap_e[blockIdx.y];
  if (e < 0) return;
  int row0 = tmap_r[blockIdx.y];
  int n0 = blockIdx.x * 128;
  const unsigned short* Ab = xe + (size_t)row0 * D_DIM;
  const unsigned short* Bb = w1t + (size_t)e * H_DIM * D_DIM + (size_t)n0 * D_DIM;
  __shared__ unsigned short As[128 * 32];
  __shared__ unsigned short Bs[128 * 32];
  int t = threadIdx.x, lane = t & 63, wid = t >> 6;
  int c0 = wid * 2, c1 = c0 + 1;
  int lr0 = c0 * 16 + (lane >> 2);
  int kc = (lane & 3) * 8;
  const unsigned short* ga0 = Ab + (size_t)lr0 * D_DIM + kc;
  const unsigned short* ga1 = ga0 + 16 * D_DIM;
  const unsigned short* gb0 = Bb + (size_t)lr0 * D_DIM + kc;
  const unsigned short* gb1 = gb0 + 16 * D_DIM;
  unsigned short* la0 = As + c0 * 512;
  unsigned short* la1 = As + c1 * 512;
  unsigned short* lb0 = Bs + c0 * 512;
  unsigned short* lb1 = Bs + c1 * 512;
  int l15 = lane & 15, q = lane >> 4;
  int wm = (wid & 1) * 64, wn = (wid >> 1) * 64;
  const unsigned short* pa[4];
  const unsigned short* pb[4];
#pragma unroll
  for (int i = 0; i < 4; i++) {
    pa[i] = As + (wm + i * 16 + l15) * 32 + q * 8;
    pb[i] = Bs + (wn + i * 16 + l15) * 32 + q * 8;
  }
  floatx4 acc[4][4];
#pragma unroll
  for (int i = 0; i < 4; i++)
#pragma unroll
    for (int j = 0; j < 4; j++) acc[i][j] = (floatx4){0.f, 0.f, 0.f, 0.f};

  for (int k0 = 0; k0 < D_DIM; k0 += 32) {
    gload_lds16(ga0, la0);
    gload_lds16(ga1, la1);
    gload_lds16(gb0, lb0);
    gload_lds16(gb1, lb1);
    __syncthreads();
    bf16x8 af[4], bfr[4];
#pragma unroll
    for (int i = 0; i < 4; i++) { af[i] = *(const bf16x8*)pa[i]; bfr[i] = *(const bf16x8*)pb[i]; }
#pragma unroll
    for (int mt = 0; mt < 4; mt++)
#pragma unroll
      for (int nt = 0; nt < 4; nt++)
        acc[mt][nt] = __builtin_amdgcn_mfma_f32_16x16x32_bf16(af[mt], bfr[nt], acc[mt][nt], 0, 0, 0);
    __syncthreads();
    ga0 += 32; ga1 += 32; gb0 += 32; gb1 += 32;
  }
  float b1v[4];
#pragma unroll
  for (int nt = 0; nt < 4; nt++) b1v[nt] = b1[(size_t)e * H_DIM + n0 + wn + nt * 16 + l15];
#pragma unroll
  for (int mt = 0; mt < 4; mt++) {
    int row = row0 + wm + mt * 16 + q * 4;
#pragma unroll
    for (int nt = 0; nt < 4; nt++) {
      int col = n0 + wn + nt * 16 + l15;
      unsigned short* hp = h + (size_t)row * H_DIM + col;
#pragma unroll
      for (int r = 0; r < 4; r++) {
        float v = acc[mt][nt][r] + b1v[nt];
        v = 0.5f * v * (1.f + erff(v * 0.70710678118f));
        hp[(size_t)r * H_DIM] = f2bf(v);
      }
    }
  }
}

// ---------------- GEMM2: out_acc[token] += w * (h @ W2[e]) ----------------
__global__ __launch_bounds__(256) void kgemm2(const unsigned short* __restrict__ h,
                                              const unsigned short* __restrict__ w2t,
                                              const int* __restrict__ slot_tok,
                                              const float* __restrict__ slot_w,
                                              float* __restrict__ out_acc,
                                              const int* __restrict__ tmap_e,
                                              const int* __restrict__ tmap_r) {
  int e = tmap_e[blockIdx.y];
  if (e < 0) return;
  int row0 = tmap_r[blockIdx.y];
  int n0 = blockIdx.x * 128;
  int kz = blockIdx.z;
  const unsigned short* Ab = h + (size_t)row0 * H_DIM + kz * 2048;
  const unsigned short* Bb = w2t + (size_t)e * C_DIM * H_DIM + (size_t)n0 * H_DIM + kz * 2048;
  __shared__ unsigned short As[128 * 32];
  __shared__ unsigned short Bs[128 * 32];
  __shared__ int stok[128];
  __shared__ float swgt[128];
  int t = threadIdx.x, lane = t & 63, wid = t >> 6;
  if (t < 128) { stok[t] = slot_tok[row0 + t]; swgt[t] = slot_w[row0 + t]; }
  int c0 = wid * 2, c1 = c0 + 1;
  int lr0 = c0 * 16 + (lane >> 2);
  int kc = (lane & 3) * 8;
  const unsigned short* ga0 = Ab + (size_t)lr0 * H_DIM + kc;
  const unsigned short* ga1 = ga0 + (size_t)16 * H_DIM;
  const unsigned short* gb0 = Bb + (size_t)lr0 * H_DIM + kc;
  const unsigned short* gb1 = gb0 + (size_t)16 * H_DIM;
  unsigned short* la0 = As + c0 * 512;
  unsigned short* la1 = As + c1 * 512;
  unsigned short* lb0 = Bs + c0 * 512;
  unsigned short* lb1 = Bs + c1 * 512;
  int l15 = lane & 15, q = lane >> 4;
  int wm = (wid & 1) * 64, wn = (wid >> 1) * 64;
  const unsigned short* pa[4];
  const unsigned short* pb[4];
#pragma unroll
  for (int i = 0; i < 4; i++) {
    pa[i] = As + (wm + i * 16 + l15) * 32 + q * 8;
    pb[i] = Bs + (wn + i * 16 + l15) * 32 + q * 8;
  }
  floatx4 acc[4][4];
#pragma unroll
  for (int i = 0; i < 4; i++)
#pragma unroll
    for (int j = 0; j < 4; j++) acc[i][j] = (floatx4){0.f, 0.f, 0.f, 0.f};

  for (int k0 = 0; k0 < 2048; k0 += 32) {
    gload_lds16(ga0, la0);
    gload_lds16(ga1, la1);
    gload_lds16(gb0, lb0);
    gload_lds16(gb1, lb1);
    __syncthreads();
    bf16x8 af[4], bfr[4];
#pragma unroll
    for (int i = 0; i < 4; i++) { af[i] = *(const bf16x8*)pa[i]; bfr[i] = *(const bf16x8*)pb[i]; }
#pragma unroll
    for (int mt = 0; mt < 4; mt++)
#pragma unroll
      for (int nt = 0; nt < 4; nt++)
        acc[mt][nt] = __builtin_amdgcn_mfma_f32_16x16x32_bf16(af[mt], bfr[nt], acc[mt][nt], 0, 0, 0);
    __syncthreads();
    ga0 += 32; ga1 += 32; gb0 += 32; gb1 += 32;
  }
#pragma unroll
  for (int mt = 0; mt < 4; mt++) {
    int rbase = wm + mt * 16 + q * 4;
#pragma unroll
    for (int nt = 0; nt < 4; nt++) {
      int col = n0 + wn + nt * 16 + l15;
#pragma unroll
      for (int r = 0; r < 4; r++) {
        int tk = stok[rbase + r];
        if (tk >= 0)
          atomicAdd(out_acc + (size_t)tk * C_DIM + col, swgt[rbase + r] * acc[mt][nt][r]);
      }
    }
  }
}

// ---------------- final: out = f32(out_acc + w0*b2[e0] + w1*b2[e1]) ----------------
__global__ __launch_bounds__(256) void kfinal(const float* __restrict__ out_acc,
                                              const int2* __restrict__ meta_i,
                                              const float4* __restrict__ meta_f,
                                              const float* __restrict__ b2,
                                              float* __restrict__ out) {
  int b = blockIdx.x, t = threadIdx.x;
  int i = t * 4;
  int2 mi = meta_i[b];
  float4 mf = meta_f[b];
  float4 a = *(const float4*)(out_acc + (size_t)b * C_DIM + i);
  float4 p = *(const float4*)(b2 + (size_t)mi.x * C_DIM + i);
  float4 qv = *(const float4*)(b2 + (size_t)mi.y * C_DIM + i);
  float4 o;
  o.x = a.x + mf.x * p.x + mf.y * qv.x;
  o.y = a.y + mf.x * p.y + mf.y * qv.y;
  o.z = a.z + mf.x * p.z + mf.y * qv.z;
  o.w = a.w + mf.x * p.w + mf.y * qv.w;
  *(float4*)(out + (size_t)b * C_DIM + i) = o;
}

extern "C" void kernel_launch(void* const* d_in, const int* in_sizes, int n_in,
                              void* d_out, int out_size, void* d_ws, size_t ws_size,
                              hipStream_t stream) {
  const float* x    = (const float*)d_in[0];
  const float* Wr   = (const float*)d_in[1];
  const float* br   = (const float*)d_in[2];
  const float* ln_g = (const float*)d_in[3];
  const float* ln_b = (const float*)d_in[4];
  const float* W1   = (const float*)d_in[5];
  const float* b1   = (const float*)d_in[6];
  const float* W2   = (const float*)d_in[7];
  const float* b2   = (const float*)d_in[8];

  char* w = (char*)d_ws;
  auto alloc = [&](size_t sz) { char* p = w; w += (sz + 255) & ~(size_t)255; return p; };
  unsigned short* W1t = (unsigned short*)alloc((size_t)E_NUM * H_DIM * D_DIM * 2);
  unsigned short* W2t = (unsigned short*)alloc((size_t)E_NUM * C_DIM * H_DIM * 2);
  unsigned short* xe  = (unsigned short*)alloc((size_t)CAP * D_DIM * 2);
  unsigned short* hb  = (unsigned short*)alloc((size_t)CAP * H_DIM * 2);
  float* out_acc      = (float*)alloc((size_t)B_TOK * C_DIM * 4);
  int2* meta_i        = (int2*)alloc((size_t)B_TOK * 8);
  float4* meta_f      = (float4*)alloc((size_t)B_TOK * 16);
  int* counts         = (int*)alloc(64);
  int* cursor         = (int*)alloc(64);
  int* tmap_e         = (int*)alloc(MAXT * 4);
  int* tmap_r         = (int*)alloc(MAXT * 4);
  int* slot_tok       = (int*)alloc(CAP * 4);
  float* slot_w       = (float*)alloc(CAP * 4);

  // transposes first (longest; independent of routing)
  hipLaunchKernelGGL(ktranspose, dim3(H_DIM / 64, D_DIM / 64, E_NUM), dim3(256), 0, stream,
                     W1, W1t, D_DIM, H_DIM);
  hipLaunchKernelGGL(ktranspose, dim3(C_DIM / 64, H_DIM / 64, E_NUM), dim3(256), 0, stream,
                     W2, W2t, H_DIM, C_DIM);
  hipLaunchKernelGGL(kinit, dim3(B_TOK * C_DIM / 256), dim3(256), 0, stream,
                     out_acc, slot_tok, counts);
  hipLaunchKernelGGL(krouter, dim3(B_TOK), dim3(256), 0, stream,
                     x, Wr, br, meta_i, meta_f, counts);
  hipLaunchKernelGGL(kprefix, dim3(1), dim3(64), 0, stream,
                     counts, cursor, tmap_e, tmap_r);
  hipLaunchKernelGGL(kscatter, dim3(B_TOK), dim3(256), 0, stream,
                     x, ln_g, ln_b, meta_i, meta_f, cursor, slot_tok, slot_w, xe);
  hipLaunchKernelGGL(kgemm1, dim3(H_DIM / 128, MAXT), dim3(256), 0, stream,
                     xe, W1t, b1, hb, tmap_e, tmap_r);
  hipLaunchKernelGGL(kgemm2, dim3(C_DIM / 128, MAXT, 2), dim3(256), 0, stream,
                     hb, W2t, slot_tok, slot_w, out_acc, tmap_e, tmap_r);
  hipLaunchKernelGGL(kfinal, dim3(B_TOK), dim3(256), 0, stream,
                     out_acc, meta_i, meta_f, b2, (float*)d_out);
}